// Round 2
// baseline (392.729 us; speedup 1.0000x reference)
//
#include <hip/hip_runtime.h>
#include <math.h>

#define N_NODES 100000
#define N_EDGES 1600000
#define OUT_F   64
#define SCAN_B  1024
#define NBLK    ((N_NODES + SCAN_B - 1) / SCAN_B)   // 98

#define EQ4      (N_EDGES / 4)                       // 400000 quads
#define HIST_BLK ((EQ4 + 255) / 256)                 // 1563
#define GEMM_BLK 512

typedef __attribute__((ext_vector_type(8))) short bf16x8;
typedef __attribute__((ext_vector_type(4))) float f32x4;

__device__ __forceinline__ unsigned short f2bf_rne(float f) {
    unsigned u = __float_as_uint(f);
    return (unsigned short)((u + 0x7fffu + ((u >> 16) & 1u)) >> 16);
}
__device__ __forceinline__ float bf2f(unsigned short h) {
    return __uint_as_float((unsigned)h << 16);
}

// ---------------------------------------------------------------------------
// Fused: blocks [0, HIST_BLK) do the edge histogram (critical path, dispatched
// first); blocks [HIST_BLK, HIST_BLK+GEMM_BLK) do G = feat @ W_h via MFMA
// (only needed by gather, overlaps the atomics). deg_i zeroed by memsetAsync.
// ---------------------------------------------------------------------------
__global__ __launch_bounds__(256) void prep_hist(
    const float* __restrict__ feat, const float* __restrict__ weight,
    const int* __restrict__ dst,
    unsigned short* __restrict__ G, unsigned* __restrict__ deg_i,
    unsigned short* __restrict__ pos)
{
    int tid = threadIdx.x;

    if (blockIdx.x < HIST_BLK) {
        // ---- histogram + per-edge position, 4 edges/thread ----
        int q = blockIdx.x * 256 + tid;
        if (q >= EQ4) return;
        int4 d = ((const int4*)dst)[q];
        ushort4 p;
        p.x = (unsigned short)atomicAdd(&deg_i[d.x], 1u);
        p.y = (unsigned short)atomicAdd(&deg_i[d.y], 1u);
        p.z = (unsigned short)atomicAdd(&deg_i[d.z], 1u);
        p.w = (unsigned short)atomicAdd(&deg_i[d.w], 1u);
        ((ushort4*)pos)[q] = p;
        return;
    }

    // ---- MFMA GEMM: D[i=out_feat][j=node], 3-term bf16 split (f32-accurate) ----
    int gb = (int)blockIdx.x - HIST_BLK;
    int wv = tid >> 6, ln = tid & 63;
    int li = ln & 15, lk = ln >> 4;

    bf16x8 Whi[4][2], Wlo[4][2];
    #pragma unroll
    for (int it = 0; it < 4; ++it)
        #pragma unroll
        for (int kb = 0; kb < 2; ++kb)
            #pragma unroll
            for (int j = 0; j < 8; ++j) {
                float w = weight[(16 + kb * 32 + lk * 8 + j) * 64 + it * 16 + li];
                unsigned short h = f2bf_rne(w);
                Whi[it][kb][j] = (short)h;
                Wlo[it][kb][j] = (short)f2bf_rne(w - bf2f(h));
            }

    const int tiles = N_NODES / 16;   // 6250 exact
    for (int tile = gb * 4 + wv; tile < tiles; tile += GEMM_BLK * 4) {
        int n = tile * 16 + li;
        const float* fr = feat + (size_t)n * 64 + lk * 8;

        bf16x8 Bhi[2], Blo[2];
        #pragma unroll
        for (int kb = 0; kb < 2; ++kb) {
            float4 v0 = *(const float4*)(fr + kb * 32);
            float4 v1 = *(const float4*)(fr + kb * 32 + 4);
            float vv[8] = {v0.x, v0.y, v0.z, v0.w, v1.x, v1.y, v1.z, v1.w};
            #pragma unroll
            for (int j = 0; j < 8; ++j) {
                unsigned short h = f2bf_rne(vv[j]);
                Bhi[kb][j] = (short)h;
                Blo[kb][j] = (short)f2bf_rne(vv[j] - bf2f(h));
            }
        }

        f32x4 acc[4] = {{0.f,0.f,0.f,0.f},{0.f,0.f,0.f,0.f},
                        {0.f,0.f,0.f,0.f},{0.f,0.f,0.f,0.f}};
        #pragma unroll
        for (int kb = 0; kb < 2; ++kb)
            #pragma unroll
            for (int it = 0; it < 4; ++it) {
                acc[it] = __builtin_amdgcn_mfma_f32_16x16x32_bf16(Whi[it][kb], Bhi[kb], acc[it], 0, 0, 0);
                acc[it] = __builtin_amdgcn_mfma_f32_16x16x32_bf16(Wlo[it][kb], Bhi[kb], acc[it], 0, 0, 0);
                acc[it] = __builtin_amdgcn_mfma_f32_16x16x32_bf16(Whi[it][kb], Blo[kb], acc[it], 0, 0, 0);
            }

        #pragma unroll
        for (int it = 0; it < 4; ++it) {
            ushort4 o;
            o.x = f2bf_rne(acc[it][0]);
            o.y = f2bf_rne(acc[it][1]);
            o.z = f2bf_rne(acc[it][2]);
            o.w = f2bf_rne(acc[it][3]);
            *(ushort4*)(G + (size_t)n * 64 + it * 16 + lk * 4) = o;
        }
    }
}

// ---------------------------------------------------------------------------
// CSR build 2a: per-block sums of deg.
// ---------------------------------------------------------------------------
__global__ __launch_bounds__(SCAN_B) void scanA(
    const unsigned* __restrict__ deg_i, unsigned* __restrict__ bsum)
{
    __shared__ unsigned ws[16];
    int i = blockIdx.x * SCAN_B + threadIdx.x;
    unsigned v = (i < N_NODES) ? deg_i[i] : 0u;
    #pragma unroll
    for (int o = 32; o; o >>= 1) v += __shfl_down(v, o);
    if ((threadIdx.x & 63) == 0) ws[threadIdx.x >> 6] = v;
    __syncthreads();
    if (threadIdx.x < 16) {
        unsigned t = ws[threadIdx.x];
        #pragma unroll
        for (int o = 8; o; o >>= 1) t += __shfl_down(t, o);
        if (threadIdx.x == 0) bsum[blockIdx.x] = t;
    }
}

// ---------------------------------------------------------------------------
// CSR build 2b: exclusive scan of deg -> off (block offset computed in-block).
// ---------------------------------------------------------------------------
__global__ __launch_bounds__(SCAN_B) void scanC(
    const unsigned* __restrict__ deg_i, const unsigned* __restrict__ bsum,
    unsigned* __restrict__ off)
{
    __shared__ unsigned ws[17];
    int t = threadIdx.x;

    if (t < 64) {
        unsigned a = 0u;
        for (int j = t; j < (int)blockIdx.x; j += 64) a += bsum[j];
        #pragma unroll
        for (int o = 32; o; o >>= 1) a += __shfl_down(a, o);
        if (t == 0) ws[16] = a;
    }

    int i = blockIdx.x * SCAN_B + t;
    unsigned v = (i < N_NODES) ? deg_i[i] : 0u;
    unsigned x = v;
    #pragma unroll
    for (int o = 1; o < 64; o <<= 1) {
        unsigned u = __shfl_up(x, o);
        if ((t & 63) >= o) x += u;
    }
    if ((t & 63) == 63) ws[t >> 6] = x;
    __syncthreads();
    if (t < 16) {
        unsigned y = ws[t];
        #pragma unroll
        for (int o = 1; o < 16; o <<= 1) {
            unsigned u = __shfl_up(y, o);
            if (t >= o) y += u;
        }
        ws[t] = y;
    }
    __syncthreads();
    unsigned base = ws[16] + ((t >> 6) ? ws[(t >> 6) - 1] : 0u);
    unsigned excl = base + x - v;
    if (i < N_NODES) off[i] = excl;
    if (i == N_NODES - 1) off[N_NODES] = excl + v;
}

// ---------------------------------------------------------------------------
// CSR build 3: atomic-free fill — slot = off[dst] + pos. 4 edges/thread.
// ---------------------------------------------------------------------------
__global__ __launch_bounds__(256) void fill_kernel(
    const int* __restrict__ src, const int* __restrict__ dst,
    const unsigned short* __restrict__ pos, const unsigned* __restrict__ off,
    unsigned long long* __restrict__ csr_pack)
{
    int q = blockIdx.x * 256 + threadIdx.x;
    if (q >= EQ4) return;
    int4 s = ((const int4*)src)[q];
    int4 d = ((const int4*)dst)[q];
    ushort4 p = ((const ushort4*)pos)[q];
    unsigned e = (unsigned)q * 4u;
    csr_pack[off[d.x] + (unsigned)p.x] =
        (unsigned long long)(unsigned)s.x | ((unsigned long long)(e + 0u) << 32);
    csr_pack[off[d.y] + (unsigned)p.y] =
        (unsigned long long)(unsigned)s.y | ((unsigned long long)(e + 1u) << 32);
    csr_pack[off[d.z] + (unsigned)p.z] =
        (unsigned long long)(unsigned)s.z | ((unsigned long long)(e + 2u) << 32);
    csr_pack[off[d.w] + (unsigned)p.w] =
        (unsigned long long)(unsigned)s.w | ((unsigned long long)(e + 3u) << 32);
}

// ---------------------------------------------------------------------------
// Gather + epilogue v2: persistent waves (We/bias amortized over ~12 nodes),
// merged G+EF inner loop (5 independent loads in flight per step-16 iter),
// nontemporal loads for read-once streams (edge_feats, csr_pack) + NT store
// for out, preserving L2 for the 16x-reused G rows.
// ---------------------------------------------------------------------------
__global__ __launch_bounds__(256) void gather_out(
    const unsigned short* __restrict__ G,
    const float* __restrict__ edge_feats,
    const unsigned long long* __restrict__ csr_pack,
    const unsigned* __restrict__ off,
    const float* __restrict__ weight,   // rows 0..15 = W_e
    const float* __restrict__ bias,
    float* __restrict__ out)
{
    int tid = threadIdx.x;
    int wv = tid >> 6, ln = tid & 63;

    float We[16];
    #pragma unroll
    for (int k = 0; k < 16; ++k) We[k] = weight[k * 64 + ln];
    float b = bias[ln];

    const float SC = 1.0507009873554805f;
    const float AL = 1.6732632423543772f;

    const int gq = ln >> 4;   // G row-group 0..3
    const int eq = ln >> 2;   // EF row-group 0..15
    const ushort4* __restrict__ Gv = (const ushort4*)G;

    for (int n = blockIdx.x * 4 + wv; n < N_NODES; n += gridDim.x * 4) {
        unsigned start = off[n], end = off[n + 1];
        float norm2 = 1.0f / fmaxf((float)(end - start), 1.0f);

        float gh4[4] = {0.f, 0.f, 0.f, 0.f};
        float ae4[4] = {0.f, 0.f, 0.f, 0.f};

        for (unsigned base = start; base < end; base += 64u) {
            unsigned m = min(64u, end - base);
            unsigned lo = 0u, hi = 0u;
            if ((unsigned)ln < m) {
                unsigned long long pk =
                    __builtin_nontemporal_load(&csr_pack[base + (unsigned)ln]);
                lo = (unsigned)pk;
                hi = (unsigned)(pk >> 32);
            }

            for (unsigned i = 0; i < m; i += 16u) {
                unsigned i0 = i + (unsigned)gq;
                unsigned i1 = i0 + 4u, i2 = i0 + 8u, i3 = i0 + 12u;
                unsigned s0 = __shfl(lo, (int)min(i0, m - 1u));
                unsigned s1 = __shfl(lo, (int)min(i1, m - 1u));
                unsigned s2 = __shfl(lo, (int)min(i2, m - 1u));
                unsigned s3 = __shfl(lo, (int)min(i3, m - 1u));
                unsigned ie = i + (unsigned)eq;
                unsigned e0 = __shfl(hi, (int)min(ie, m - 1u));

                ushort4 q0 = {0,0,0,0}, q1 = {0,0,0,0},
                        q2 = {0,0,0,0}, q3 = {0,0,0,0};
                if (i0 < m) q0 = Gv[(size_t)s0 * 16u + (unsigned)(ln & 15)];
                if (i1 < m) q1 = Gv[(size_t)s1 * 16u + (unsigned)(ln & 15)];
                if (i2 < m) q2 = Gv[(size_t)s2 * 16u + (unsigned)(ln & 15)];
                if (i3 < m) q3 = Gv[(size_t)s3 * 16u + (unsigned)(ln & 15)];

                f32x4 v = {0.f, 0.f, 0.f, 0.f};
                if (ie < m)
                    v = __builtin_nontemporal_load(
                        (const f32x4*)(edge_feats + (size_t)e0 * 16u + (unsigned)(ln & 3) * 4u));

                gh4[0] += __uint_as_float((unsigned)q0.x << 16) + __uint_as_float((unsigned)q1.x << 16)
                        + __uint_as_float((unsigned)q2.x << 16) + __uint_as_float((unsigned)q3.x << 16);
                gh4[1] += __uint_as_float((unsigned)q0.y << 16) + __uint_as_float((unsigned)q1.y << 16)
                        + __uint_as_float((unsigned)q2.y << 16) + __uint_as_float((unsigned)q3.y << 16);
                gh4[2] += __uint_as_float((unsigned)q0.z << 16) + __uint_as_float((unsigned)q1.z << 16)
                        + __uint_as_float((unsigned)q2.z << 16) + __uint_as_float((unsigned)q3.z << 16);
                gh4[3] += __uint_as_float((unsigned)q0.w << 16) + __uint_as_float((unsigned)q1.w << 16)
                        + __uint_as_float((unsigned)q2.w << 16) + __uint_as_float((unsigned)q3.w << 16);
                ae4[0] += v[0]; ae4[1] += v[1]; ae4[2] += v[2]; ae4[3] += v[3];
            }
        }

        #pragma unroll
        for (int c = 0; c < 4; ++c) {
            gh4[c] += __shfl_xor(gh4[c], 16);
            gh4[c] += __shfl_xor(gh4[c], 32);
            ae4[c] += __shfl_xor(ae4[c], 4);
            ae4[c] += __shfl_xor(ae4[c], 8);
            ae4[c] += __shfl_xor(ae4[c], 16);
            ae4[c] += __shfl_xor(ae4[c], 32);
        }
        int srcl = ln >> 2;
        float r0 = __shfl(gh4[0], srcl);
        float r1 = __shfl(gh4[1], srcl);
        float r2 = __shfl(gh4[2], srcl);
        float r3 = __shfl(gh4[3], srcl);
        int c = ln & 3;
        float gh = (c & 2) ? ((c & 1) ? r3 : r2) : ((c & 1) ? r1 : r0);

        float acc = gh;
        #pragma unroll
        for (int k = 0; k < 16; ++k)
            acc = fmaf(__shfl(ae4[k & 3], k >> 2), We[k], acc);

        float o = acc * norm2 + b;
        float res = (o > 0.f) ? SC * o : SC * AL * expm1f(o);
        __builtin_nontemporal_store(res, &out[(size_t)n * 64u + ln]);
    }
}

extern "C" void kernel_launch(void* const* d_in, const int* in_sizes, int n_in,
                              void* d_out, int out_size, void* d_ws, size_t ws_size,
                              hipStream_t stream) {
    const float* feat       = (const float*)d_in[0];
    const float* edge_feats = (const float*)d_in[1];
    const int*   src        = (const int*)d_in[2];
    const int*   dst        = (const int*)d_in[3];
    const float* weight     = (const float*)d_in[4];
    const float* bias       = (const float*)d_in[5];
    float* out = (float*)d_out;

    // ws: csr_pack 12.8MB | G 12.8MB | pos 3.2MB | deg_i | off(+1) | bsum
    unsigned long long* csr_pack = (unsigned long long*)d_ws;
    unsigned short* G   = (unsigned short*)(csr_pack + N_EDGES);
    unsigned short* pos = G + (size_t)N_NODES * 64;
    unsigned* deg_i = (unsigned*)(pos + N_EDGES);
    unsigned* off   = deg_i + N_NODES;            // N_NODES + 1
    unsigned* bsum  = off + N_NODES + 1;          // NBLK

    hipMemsetAsync(deg_i, 0, N_NODES * sizeof(unsigned), stream);
    prep_hist<<<dim3(HIST_BLK + GEMM_BLK), dim3(256), 0, stream>>>(
        feat, weight, dst, G, deg_i, pos);
    scanA<<<dim3(NBLK), dim3(SCAN_B), 0, stream>>>(deg_i, bsum);
    scanC<<<dim3(NBLK), dim3(SCAN_B), 0, stream>>>(deg_i, bsum, off);
    fill_kernel<<<dim3(HIST_BLK), dim3(256), 0, stream>>>(
        src, dst, pos, off, csr_pack);
    gather_out<<<dim3(2048), dim3(256), 0, stream>>>(
        G, edge_feats, csr_pack, off, weight, bias, out);
}

// Round 3
// 355.553 us; speedup vs baseline: 1.1046x; 1.1046x over previous
//
#include <hip/hip_runtime.h>
#include <math.h>

#define N_NODES 100000
#define N_EDGES 1600000
#define OUT_F   64
#define SCAN_B  1024
#define NBLK    ((N_NODES + SCAN_B - 1) / SCAN_B)   // 98

#define EQ4      (N_EDGES / 4)                       // 400000 quads
#define HIST_BLK ((EQ4 + 255) / 256)                 // 1563
#define GEMM_BLK 512

typedef __attribute__((ext_vector_type(8))) short bf16x8;
typedef __attribute__((ext_vector_type(4))) float f32x4;

__device__ __forceinline__ unsigned short f2bf_rne(float f) {
    unsigned u = __float_as_uint(f);
    return (unsigned short)((u + 0x7fffu + ((u >> 16) & 1u)) >> 16);
}
__device__ __forceinline__ float bf2f(unsigned short h) {
    return __uint_as_float((unsigned)h << 16);
}

// ---------------------------------------------------------------------------
// Fused: blocks [0, HIST_BLK) do the edge histogram (critical path, dispatched
// first); blocks [HIST_BLK, HIST_BLK+GEMM_BLK) do G = feat @ W_h via MFMA
// (only needed by gather, overlaps the atomics). deg_i zeroed by memsetAsync.
// ---------------------------------------------------------------------------
__global__ __launch_bounds__(256) void prep_hist(
    const float* __restrict__ feat, const float* __restrict__ weight,
    const int* __restrict__ dst,
    unsigned short* __restrict__ G, unsigned* __restrict__ deg_i,
    unsigned short* __restrict__ pos)
{
    int tid = threadIdx.x;

    if (blockIdx.x < HIST_BLK) {
        // ---- histogram + per-edge position, 4 edges/thread ----
        int q = blockIdx.x * 256 + tid;
        if (q >= EQ4) return;
        int4 d = ((const int4*)dst)[q];
        ushort4 p;
        p.x = (unsigned short)atomicAdd(&deg_i[d.x], 1u);
        p.y = (unsigned short)atomicAdd(&deg_i[d.y], 1u);
        p.z = (unsigned short)atomicAdd(&deg_i[d.z], 1u);
        p.w = (unsigned short)atomicAdd(&deg_i[d.w], 1u);
        ((ushort4*)pos)[q] = p;
        return;
    }

    // ---- MFMA GEMM: D[i=out_feat][j=node], 3-term bf16 split (f32-accurate) ----
    int gb = (int)blockIdx.x - HIST_BLK;
    int wv = tid >> 6, ln = tid & 63;
    int li = ln & 15, lk = ln >> 4;

    bf16x8 Whi[4][2], Wlo[4][2];
    #pragma unroll
    for (int it = 0; it < 4; ++it)
        #pragma unroll
        for (int kb = 0; kb < 2; ++kb)
            #pragma unroll
            for (int j = 0; j < 8; ++j) {
                float w = weight[(16 + kb * 32 + lk * 8 + j) * 64 + it * 16 + li];
                unsigned short h = f2bf_rne(w);
                Whi[it][kb][j] = (short)h;
                Wlo[it][kb][j] = (short)f2bf_rne(w - bf2f(h));
            }

    const int tiles = N_NODES / 16;   // 6250 exact
    for (int tile = gb * 4 + wv; tile < tiles; tile += GEMM_BLK * 4) {
        int n = tile * 16 + li;
        const float* fr = feat + (size_t)n * 64 + lk * 8;

        bf16x8 Bhi[2], Blo[2];
        #pragma unroll
        for (int kb = 0; kb < 2; ++kb) {
            float4 v0 = *(const float4*)(fr + kb * 32);
            float4 v1 = *(const float4*)(fr + kb * 32 + 4);
            float vv[8] = {v0.x, v0.y, v0.z, v0.w, v1.x, v1.y, v1.z, v1.w};
            #pragma unroll
            for (int j = 0; j < 8; ++j) {
                unsigned short h = f2bf_rne(vv[j]);
                Bhi[kb][j] = (short)h;
                Blo[kb][j] = (short)f2bf_rne(vv[j] - bf2f(h));
            }
        }

        f32x4 acc[4] = {{0.f,0.f,0.f,0.f},{0.f,0.f,0.f,0.f},
                        {0.f,0.f,0.f,0.f},{0.f,0.f,0.f,0.f}};
        #pragma unroll
        for (int kb = 0; kb < 2; ++kb)
            #pragma unroll
            for (int it = 0; it < 4; ++it) {
                acc[it] = __builtin_amdgcn_mfma_f32_16x16x32_bf16(Whi[it][kb], Bhi[kb], acc[it], 0, 0, 0);
                acc[it] = __builtin_amdgcn_mfma_f32_16x16x32_bf16(Wlo[it][kb], Bhi[kb], acc[it], 0, 0, 0);
                acc[it] = __builtin_amdgcn_mfma_f32_16x16x32_bf16(Whi[it][kb], Blo[kb], acc[it], 0, 0, 0);
            }

        #pragma unroll
        for (int it = 0; it < 4; ++it) {
            ushort4 o;
            o.x = f2bf_rne(acc[it][0]);
            o.y = f2bf_rne(acc[it][1]);
            o.z = f2bf_rne(acc[it][2]);
            o.w = f2bf_rne(acc[it][3]);
            *(ushort4*)(G + (size_t)n * 64 + it * 16 + lk * 4) = o;
        }
    }
}

// ---------------------------------------------------------------------------
// CSR build 2a: per-block sums of deg.
// ---------------------------------------------------------------------------
__global__ __launch_bounds__(SCAN_B) void scanA(
    const unsigned* __restrict__ deg_i, unsigned* __restrict__ bsum)
{
    __shared__ unsigned ws[16];
    int i = blockIdx.x * SCAN_B + threadIdx.x;
    unsigned v = (i < N_NODES) ? deg_i[i] : 0u;
    #pragma unroll
    for (int o = 32; o; o >>= 1) v += __shfl_down(v, o);
    if ((threadIdx.x & 63) == 0) ws[threadIdx.x >> 6] = v;
    __syncthreads();
    if (threadIdx.x < 16) {
        unsigned t = ws[threadIdx.x];
        #pragma unroll
        for (int o = 8; o; o >>= 1) t += __shfl_down(t, o);
        if (threadIdx.x == 0) bsum[blockIdx.x] = t;
    }
}

// ---------------------------------------------------------------------------
// CSR build 2b: exclusive scan of deg -> off (block offset computed in-block).
// ---------------------------------------------------------------------------
__global__ __launch_bounds__(SCAN_B) void scanC(
    const unsigned* __restrict__ deg_i, const unsigned* __restrict__ bsum,
    unsigned* __restrict__ off)
{
    __shared__ unsigned ws[17];
    int t = threadIdx.x;

    if (t < 64) {
        unsigned a = 0u;
        for (int j = t; j < (int)blockIdx.x; j += 64) a += bsum[j];
        #pragma unroll
        for (int o = 32; o; o >>= 1) a += __shfl_down(a, o);
        if (t == 0) ws[16] = a;
    }

    int i = blockIdx.x * SCAN_B + t;
    unsigned v = (i < N_NODES) ? deg_i[i] : 0u;
    unsigned x = v;
    #pragma unroll
    for (int o = 1; o < 64; o <<= 1) {
        unsigned u = __shfl_up(x, o);
        if ((t & 63) >= o) x += u;
    }
    if ((t & 63) == 63) ws[t >> 6] = x;
    __syncthreads();
    if (t < 16) {
        unsigned y = ws[t];
        #pragma unroll
        for (int o = 1; o < 16; o <<= 1) {
            unsigned u = __shfl_up(y, o);
            if (t >= o) y += u;
        }
        ws[t] = y;
    }
    __syncthreads();
    unsigned base = ws[16] + ((t >> 6) ? ws[(t >> 6) - 1] : 0u);
    unsigned excl = base + x - v;
    if (i < N_NODES) off[i] = excl;
    if (i == N_NODES - 1) off[N_NODES] = excl + v;
}

// ---------------------------------------------------------------------------
// CSR build 3: atomic-free fill — slot = off[dst] + pos. 4 edges/thread.
// ---------------------------------------------------------------------------
__global__ __launch_bounds__(256) void fill_kernel(
    const int* __restrict__ src, const int* __restrict__ dst,
    const unsigned short* __restrict__ pos, const unsigned* __restrict__ off,
    unsigned long long* __restrict__ csr_pack)
{
    int q = blockIdx.x * 256 + threadIdx.x;
    if (q >= EQ4) return;
    int4 s = ((const int4*)src)[q];
    int4 d = ((const int4*)dst)[q];
    ushort4 p = ((const ushort4*)pos)[q];
    unsigned e = (unsigned)q * 4u;
    csr_pack[off[d.x] + (unsigned)p.x] =
        (unsigned long long)(unsigned)s.x | ((unsigned long long)(e + 0u) << 32);
    csr_pack[off[d.y] + (unsigned)p.y] =
        (unsigned long long)(unsigned)s.y | ((unsigned long long)(e + 1u) << 32);
    csr_pack[off[d.z] + (unsigned)p.z] =
        (unsigned long long)(unsigned)s.z | ((unsigned long long)(e + 2u) << 32);
    csr_pack[off[d.w] + (unsigned)p.w] =
        (unsigned long long)(unsigned)s.w | ((unsigned long long)(e + 3u) << 32);
}

// ---------------------------------------------------------------------------
// Gather + epilogue — EXACT R1 version (proven 100.6 µs): one node per wave,
// oversubscribed 25000-block grid (block refill keeps occupancy ~75%),
// separate G (step-8) and EF (step-16) inner loops, plain (cached) loads.
// ---------------------------------------------------------------------------
__global__ __launch_bounds__(256) void gather_out(
    const unsigned short* __restrict__ G,
    const float* __restrict__ edge_feats,
    const unsigned long long* __restrict__ csr_pack,
    const unsigned* __restrict__ off,
    const float* __restrict__ weight,   // rows 0..15 = W_e
    const float* __restrict__ bias,
    float* __restrict__ out)
{
    int tid = threadIdx.x;
    int wv = tid >> 6, ln = tid & 63;

    float We[16];
    #pragma unroll
    for (int k = 0; k < 16; ++k) We[k] = weight[k * 64 + ln];
    float b = bias[ln];

    const float SC = 1.0507009873554805f;
    const float AL = 1.6732632423543772f;

    int n = blockIdx.x * 4 + wv;
    if (n >= N_NODES) return;

    unsigned start = off[n], end = off[n + 1];
    float norm2 = 1.0f / fmaxf((float)(end - start), 1.0f);

    const int gq = ln >> 4;   // G row-group 0..3
    const int eq = ln >> 2;   // EF row-group 0..15

    float gh4[4] = {0.f, 0.f, 0.f, 0.f};
    float ae4[4] = {0.f, 0.f, 0.f, 0.f};

    const ushort4* __restrict__ Gv = (const ushort4*)G;

    for (unsigned base = start; base < end; base += 64u) {
        unsigned m = min(64u, end - base);
        unsigned lo = 0u, hi = 0u;
        if ((unsigned)ln < m) {
            unsigned long long pk = csr_pack[base + (unsigned)ln];
            lo = (unsigned)pk;
            hi = (unsigned)(pk >> 32);
        }

        for (unsigned i = 0; i < m; i += 8u) {
            unsigned i0 = i + (unsigned)gq, i1 = i0 + 4u;
            unsigned s0 = __shfl(lo, (int)min(i0, m - 1u));
            unsigned s1 = __shfl(lo, (int)min(i1, m - 1u));
            ushort4 q0 = {0,0,0,0}, q1 = {0,0,0,0};
            if (i0 < m) q0 = Gv[(size_t)s0 * 16u + (unsigned)(ln & 15)];
            if (i1 < m) q1 = Gv[(size_t)s1 * 16u + (unsigned)(ln & 15)];
            gh4[0] += __uint_as_float((unsigned)q0.x << 16) + __uint_as_float((unsigned)q1.x << 16);
            gh4[1] += __uint_as_float((unsigned)q0.y << 16) + __uint_as_float((unsigned)q1.y << 16);
            gh4[2] += __uint_as_float((unsigned)q0.z << 16) + __uint_as_float((unsigned)q1.z << 16);
            gh4[3] += __uint_as_float((unsigned)q0.w << 16) + __uint_as_float((unsigned)q1.w << 16);
        }

        for (unsigned i = 0; i < m; i += 16u) {
            unsigned ie = i + (unsigned)eq;
            unsigned e0 = __shfl(hi, (int)min(ie, m - 1u));
            if (ie < m) {
                float4 v = *(const float4*)(edge_feats + (size_t)e0 * 16u + (unsigned)(ln & 3) * 4u);
                ae4[0] += v.x; ae4[1] += v.y; ae4[2] += v.z; ae4[3] += v.w;
            }
        }
    }

    #pragma unroll
    for (int c = 0; c < 4; ++c) {
        gh4[c] += __shfl_xor(gh4[c], 16);
        gh4[c] += __shfl_xor(gh4[c], 32);
        ae4[c] += __shfl_xor(ae4[c], 4);
        ae4[c] += __shfl_xor(ae4[c], 8);
        ae4[c] += __shfl_xor(ae4[c], 16);
        ae4[c] += __shfl_xor(ae4[c], 32);
    }
    int srcl = ln >> 2;
    float r0 = __shfl(gh4[0], srcl);
    float r1 = __shfl(gh4[1], srcl);
    float r2 = __shfl(gh4[2], srcl);
    float r3 = __shfl(gh4[3], srcl);
    int c = ln & 3;
    float gh = (c & 2) ? ((c & 1) ? r3 : r2) : ((c & 1) ? r1 : r0);

    float acc = gh;
    #pragma unroll
    for (int k = 0; k < 16; ++k)
        acc = fmaf(__shfl(ae4[k & 3], k >> 2), We[k], acc);

    float o = acc * norm2 + b;
    out[(size_t)n * 64u + ln] = (o > 0.f) ? SC * o : SC * AL * expm1f(o);
}

extern "C" void kernel_launch(void* const* d_in, const int* in_sizes, int n_in,
                              void* d_out, int out_size, void* d_ws, size_t ws_size,
                              hipStream_t stream) {
    const float* feat       = (const float*)d_in[0];
    const float* edge_feats = (const float*)d_in[1];
    const int*   src        = (const int*)d_in[2];
    const int*   dst        = (const int*)d_in[3];
    const float* weight     = (const float*)d_in[4];
    const float* bias       = (const float*)d_in[5];
    float* out = (float*)d_out;

    // ws: csr_pack 12.8MB | G 12.8MB | pos 3.2MB | deg_i | off(+1) | bsum
    unsigned long long* csr_pack = (unsigned long long*)d_ws;
    unsigned short* G   = (unsigned short*)(csr_pack + N_EDGES);
    unsigned short* pos = G + (size_t)N_NODES * 64;
    unsigned* deg_i = (unsigned*)(pos + N_EDGES);
    unsigned* off   = deg_i + N_NODES;            // N_NODES + 1
    unsigned* bsum  = off + N_NODES + 1;          // NBLK

    hipMemsetAsync(deg_i, 0, N_NODES * sizeof(unsigned), stream);
    prep_hist<<<dim3(HIST_BLK + GEMM_BLK), dim3(256), 0, stream>>>(
        feat, weight, dst, G, deg_i, pos);
    scanA<<<dim3(NBLK), dim3(SCAN_B), 0, stream>>>(deg_i, bsum);
    scanC<<<dim3(NBLK), dim3(SCAN_B), 0, stream>>>(deg_i, bsum, off);
    fill_kernel<<<dim3(HIST_BLK), dim3(256), 0, stream>>>(
        src, dst, pos, off, csr_pack);
    gather_out<<<dim3((N_NODES + 3) / 4), dim3(256), 0, stream>>>(
        G, edge_feats, csr_pack, off, weight, bias, out);
}